// Round 1
// 1437.304 us; speedup vs baseline: 1.4527x; 1.4527x over previous
//
#include <hip/hip_runtime.h>
#include <hip/hip_fp16.h>
#include <stdint.h>

// Problem constants (fixed by the reference file)
#define M_DIM 8192    // B*S = 4*2048
#define K_DIM 4096    // IN_F
#define N_DIM 11008   // OUT_F

// Harness dtype model (round-1/2 forensics, verified passing):
//   x, scale, bias: fp16 values delivered as float32 buffers
//   qweight: int8 values delivered as int32 (sniff confirms) or raw int8
//   output: float32 buffer
// All values are exactly fp16-representable -> f16 MFMA is exact.

typedef _Float16 f16x8 __attribute__((ext_vector_type(8)));  // 8 fp16 = 4 VGPRs
typedef float f32x4 __attribute__((ext_vector_type(4)));     // MFMA 16x16 acc

typedef const void __attribute__((address_space(1)))* gptr_t;
typedef void __attribute__((address_space(3)))* lptr_t;

__device__ __forceinline__ void async_load16(const void* g, void* l) {
    // global -> LDS DMA, 16B per lane. LDS dest must be wave-uniform base +
    // lane*16 (it is: we pass linear tid*16 addresses).
    __builtin_amdgcn_global_load_lds((gptr_t)g, (lptr_t)l, 16, 0, 0);
}

// ---------------------------------------------------------------------------
// sniff: decide whether qweight arrived as int32 (harness-upcast) or raw int8.
// int32 data: 4096 consecutive words all in [-127,127]. Raw int8 words are
// 4 random bytes -> essentially never passes.
// ---------------------------------------------------------------------------
__global__ void sniff_kernel(const int* __restrict__ q, int* __restrict__ flag) {
    __shared__ int s;
    if (threadIdx.x == 0) s = 1;
    __syncthreads();
    int bad = 0;
#pragma unroll
    for (int i = 0; i < 16; ++i) {
        int v = q[threadIdx.x * 16 + i];
        if (v < -127 || v > 127) bad = 1;
    }
    if (bad) s = 0;   // benign race: all writers write 0
    __syncthreads();
    if (threadIdx.x == 0) flag[0] = s;
}

// ---------------------------------------------------------------------------
// Convert passes: one streaming read+write each, then the GEMM runs pure f16.
// ---------------------------------------------------------------------------
__global__ __launch_bounds__(256)
void cvt_x_kernel(const float* __restrict__ in, _Float16* __restrict__ out) {
    const size_t n8 = (size_t)M_DIM * K_DIM / 8;       // 4,194,304 chunks
    const size_t stride = (size_t)gridDim.x * 256;
    for (size_t i = (size_t)blockIdx.x * 256 + threadIdx.x; i < n8; i += stride) {
        const float4* p = (const float4*)(in + i * 8);
        float4 a = p[0], b = p[1];
        f16x8 h;
        h[0] = (_Float16)a.x; h[1] = (_Float16)a.y;
        h[2] = (_Float16)a.z; h[3] = (_Float16)a.w;
        h[4] = (_Float16)b.x; h[5] = (_Float16)b.y;
        h[6] = (_Float16)b.z; h[7] = (_Float16)b.w;
        *(f16x8*)(out + i * 8) = h;
    }
}

__global__ __launch_bounds__(256)
void cvt_w_kernel(const void* __restrict__ in, _Float16* __restrict__ out,
                  const int* __restrict__ flag) {
    const bool w_is_i32 = (flag[0] != 0);              // uniform branch
    const size_t n8 = (size_t)N_DIM * K_DIM / 8;       // 5,636,096 chunks
    const size_t stride = (size_t)gridDim.x * 256;
    if (w_is_i32) {
        const int* q = (const int*)in;
        for (size_t i = (size_t)blockIdx.x * 256 + threadIdx.x; i < n8; i += stride) {
            const int4* p = (const int4*)(q + i * 8);
            int4 a = p[0], b = p[1];
            f16x8 h;
            h[0] = (_Float16)a.x; h[1] = (_Float16)a.y;
            h[2] = (_Float16)a.z; h[3] = (_Float16)a.w;
            h[4] = (_Float16)b.x; h[5] = (_Float16)b.y;
            h[6] = (_Float16)b.z; h[7] = (_Float16)b.w;
            *(f16x8*)(out + i * 8) = h;
        }
    } else {
        const signed char* q = (const signed char*)in;
        for (size_t i = (size_t)blockIdx.x * 256 + threadIdx.x; i < n8; i += stride) {
            const int2* p = (const int2*)(q + i * 8);
            int2 raw = p[0];
            f16x8 h;
            h[0] = (_Float16)(signed char)(raw.x & 0xff);
            h[1] = (_Float16)(signed char)((raw.x >> 8) & 0xff);
            h[2] = (_Float16)(signed char)((raw.x >> 16) & 0xff);
            h[3] = (_Float16)(signed char)((raw.x >> 24) & 0xff);
            h[4] = (_Float16)(signed char)(raw.y & 0xff);
            h[5] = (_Float16)(signed char)((raw.y >> 8) & 0xff);
            h[6] = (_Float16)(signed char)((raw.y >> 16) & 0xff);
            h[7] = (_Float16)(signed char)((raw.y >> 24) & 0xff);
            *(f16x8*)(out + i * 8) = h;
        }
    }
}

// ---------------------------------------------------------------------------
// Fast path: f16 x f16 GEMM, m97 structure.
//   128x128 tile, BK=64, 4 waves (2x2 of 64x64), global_load_lds dwordx4
//   staging, XOR-swizzled LDS (inverse-swizzled global src + swizzled ds_read
//   -- rule #21), XCD-chunked block mapping (5504 % 8 == 0).
// ---------------------------------------------------------------------------
#define BM 128
#define BN 128
#define FBK 64
#define TM (M_DIM / BM)   // 64
#define TN (N_DIM / BN)   // 86
#define NWG (TM * TN)     // 5504; 5504 % 8 == 0 -> simple XCD swizzle bijective
#define PER_XCD (NWG / 8) // 688 = one 8-m-tile group x all 86 n-tiles

__global__ __launch_bounds__(256)
void f16_gemm_kernel(const _Float16* __restrict__ A,   // [M,K] f16
                     const _Float16* __restrict__ W,   // [N,K] f16
                     const float* __restrict__ scale,  // [N]
                     const float* __restrict__ bias,   // [N]
                     float* __restrict__ C)            // [M,N] f32
{
    __shared__ __align__(16) _Float16 As[BM * FBK];   // 16 KB
    __shared__ __align__(16) _Float16 Bs[BN * FBK];   // 16 KB

    const int tid  = threadIdx.x;
    const int wave = tid >> 6;
    const int lane = tid & 63;
    const int quad = lane >> 4;
    const int col  = lane & 15;

    // XCD-chunked mapping: blocks with bid%8==x (round-robin to XCD x) own
    // m-group x (m-tiles 8x..8x+7) sweeping all n-tiles. Per-K-step working
    // set ~320 KB << 4 MB XCD-L2; the whole f16 W panel (90 MB) is
    // LLC-resident across XCDs.
    const int bid = blockIdx.x;
    const int xcd = bid & 7;
    const int r   = bid >> 3;            // 0..687
    const int bm  = xcd * 8 + (r & 7);   // 0..63
    const int bn  = r >> 3;              // 0..85

    const int m0 = bm * BM;
    const int n0 = bn * BN;
    const int wm = (wave >> 1) * 64;
    const int wn = (wave & 1) * 64;

    f32x4 acc[4][4];
#pragma unroll
    for (int mi = 0; mi < 4; ++mi)
#pragma unroll
        for (int ni = 0; ni < 4; ++ni)
            acc[mi][ni] = (f32x4){0.f, 0.f, 0.f, 0.f};

    // Staging geometry: tile row = i*32 + tid/8, 16B chunk = tid%8 (8 chunks
    // of 8 f16 per 128B row). LDS dest is LINEAR (gl_lds requirement); the
    // GLOBAL source chunk is XOR-swizzled so that LDS[row][c] holds global
    // chunk c ^ (row&7). The ds_read below applies the same XOR -> identity.
    const int srow   = tid >> 3;                       // 0..31
    const int schunk = (tid & 7) ^ (srow & 7);         // inverse-swizzled src
    const _Float16* ga = A + (size_t)(m0 + srow) * K_DIM + schunk * 8;
    const _Float16* gw = W + (size_t)(n0 + srow) * K_DIM + schunk * 8;
    _Float16* la = As + tid * 8;
    _Float16* lb = Bs + tid * 8;

    for (int k0 = 0; k0 < K_DIM; k0 += FBK) {
        // ---- stage A+W tiles: 8 x global_load_lds_dwordx4 per thread ----
#pragma unroll
        for (int i = 0; i < 4; ++i) {
            async_load16(ga + (size_t)i * 32 * K_DIM + k0, la + i * 2048);
            async_load16(gw + (size_t)i * 32 * K_DIM + k0, lb + i * 2048);
        }
        __syncthreads();   // drains vmcnt(0): DMA complete for all waves

        // ---- fragments -> 32 MFMAs ----
        // Fragment (mi, ks): A[row=wm+mi*16+col][k = ks*32 + quad*8 + j].
        // Row-major As[128][64] has 128B rows -> unswizzled this is a 16-way
        // conflict; XOR of row&7 (== col&7 here) into the chunk index makes
        // every 8 consecutive rows cover all 8 chunks -> 2-way max (free).
#pragma unroll
        for (int ks = 0; ks < 2; ++ks) {
            const int cx = ((ks * 4 + quad) ^ (col & 7)) * 8;
            f16x8 af[4], bf[4];
#pragma unroll
            for (int mi = 0; mi < 4; ++mi)
                af[mi] = *(const f16x8*)(As + (wm + mi * 16 + col) * FBK + cx);
#pragma unroll
            for (int ni = 0; ni < 4; ++ni)
                bf[ni] = *(const f16x8*)(Bs + (wn + ni * 16 + col) * FBK + cx);
#pragma unroll
            for (int mi = 0; mi < 4; ++mi)
#pragma unroll
                for (int ni = 0; ni < 4; ++ni)
                    acc[mi][ni] = __builtin_amdgcn_mfma_f32_16x16x32_f16(
                        af[mi], bf[ni], acc[mi][ni], 0, 0, 0);
        }
        __syncthreads();   // all reads done before next stage overwrites
    }

    // ---- epilogue: C/D map col=lane&15, row=quad*4+reg (m89-verified) ----
    float scl[4], bsv[4];
#pragma unroll
    for (int ni = 0; ni < 4; ++ni) {
        int n = n0 + wn + ni * 16 + col;
        scl[ni] = scale[n];
        bsv[ni] = bias[n];
    }
#pragma unroll
    for (int mi = 0; mi < 4; ++mi) {
#pragma unroll
        for (int rr = 0; rr < 4; ++rr) {
            int m = m0 + wm + mi * 16 + quad * 4 + rr;
            float* cp = C + (size_t)m * N_DIM + n0 + wn + col;
#pragma unroll
            for (int ni = 0; ni < 4; ++ni) {
                cp[ni * 16] = acc[mi][ni][rr] * scl[ni] + bsv[ni];
            }
        }
    }
}

// ---------------------------------------------------------------------------
// Fallback (workspace too small): previous verified kernel, unchanged.
// ---------------------------------------------------------------------------
#define OBK 32

__global__ __launch_bounds__(256)
void w8_gemm_kernel(const float* __restrict__ A,      // f32 (fp16 values) [M,K]
                    const void* __restrict__ Wv,      // int32 or int8 [N,K]
                    const float* __restrict__ scale,  // f32 [N]
                    const float* __restrict__ bias,   // f32 [N]
                    float* __restrict__ C,            // f32 [M,N]
                    const int* __restrict__ flag)
{
    __shared__ __align__(16) _Float16 As[BM * OBK];   // 8 KB
    __shared__ __align__(16) _Float16 Bs[BN * OBK];   // 8 KB

    const int tid  = threadIdx.x;
    const int wave = tid >> 6;
    const int lane = tid & 63;
    const int quad = lane >> 4;
    const int col  = lane & 15;

    const bool w_is_i32 = (flag[0] != 0);

    int bid = blockIdx.x;
    const int per_group = 8 * TN;
    int g = bid / per_group;
    int r = bid - g * per_group;
    const int bm = g * 8 + (r & 7);
    const int bn = r >> 3;

    const int m0 = bm * BM;
    const int n0 = bn * BN;
    const int wm = (wave >> 1) * 64;
    const int wn = (wave & 1) * 64;

    f32x4 acc[4][4];
#pragma unroll
    for (int mi = 0; mi < 4; ++mi)
#pragma unroll
        for (int ni = 0; ni < 4; ++ni)
            acc[mi][ni] = (f32x4){0.f, 0.f, 0.f, 0.f};

    for (int k0 = 0; k0 < K_DIM; k0 += OBK) {
#pragma unroll
        for (int i = 0; i < 2; ++i) {
            int idx = i * 256 + tid;
            int row = idx >> 2;
            int c   = idx & 3;
            const float4* p = (const float4*)(A + (size_t)(m0 + row) * K_DIM + k0 + c * 8);
            float4 v0 = p[0];
            float4 v1 = p[1];
            f16x8 h;
            h[0] = (_Float16)v0.x; h[1] = (_Float16)v0.y;
            h[2] = (_Float16)v0.z; h[3] = (_Float16)v0.w;
            h[4] = (_Float16)v1.x; h[5] = (_Float16)v1.y;
            h[6] = (_Float16)v1.z; h[7] = (_Float16)v1.w;
            *(f16x8*)(As + idx * 8) = h;
        }
        if (w_is_i32) {
            const int* Wq = (const int*)Wv;
#pragma unroll
            for (int i = 0; i < 2; ++i) {
                int idx = i * 256 + tid;
                int row = idx >> 2;
                int c   = idx & 3;
                const int4* p = (const int4*)(Wq + (size_t)(n0 + row) * K_DIM + k0 + c * 8);
                int4 a = p[0];
                int4 b = p[1];
                f16x8 h;
                h[0] = (_Float16)a.x; h[1] = (_Float16)a.y;
                h[2] = (_Float16)a.z; h[3] = (_Float16)a.w;
                h[4] = (_Float16)b.x; h[5] = (_Float16)b.y;
                h[6] = (_Float16)b.z; h[7] = (_Float16)b.w;
                *(f16x8*)(Bs + idx * 8) = h;
            }
        } else {
            const signed char* W8 = (const signed char*)Wv;
#pragma unroll
            for (int i = 0; i < 2; ++i) {
                int idx = i * 256 + tid;
                int row = idx >> 2;
                int c   = idx & 3;
                const int2* p = (const int2*)(W8 + (size_t)(n0 + row) * K_DIM + k0 + c * 8);
                int2 raw = p[0];
                f16x8 h;
                h[0] = (_Float16)(signed char)(raw.x & 0xff);
                h[1] = (_Float16)(signed char)((raw.x >> 8) & 0xff);
                h[2] = (_Float16)(signed char)((raw.x >> 16) & 0xff);
                h[3] = (_Float16)(signed char)((raw.x >> 24) & 0xff);
                h[4] = (_Float16)(signed char)(raw.y & 0xff);
                h[5] = (_Float16)(signed char)((raw.y >> 8) & 0xff);
                h[6] = (_Float16)(signed char)((raw.y >> 16) & 0xff);
                h[7] = (_Float16)(signed char)((raw.y >> 24) & 0xff);
                *(f16x8*)(Bs + idx * 8) = h;
            }
        }
        __syncthreads();

        f16x8 af[4], bfr[4];
#pragma unroll
        for (int mi = 0; mi < 4; ++mi)
            af[mi] = *(const f16x8*)(As + (wm + mi * 16 + col) * OBK + quad * 8);
#pragma unroll
        for (int ni = 0; ni < 4; ++ni)
            bfr[ni] = *(const f16x8*)(Bs + (wn + ni * 16 + col) * OBK + quad * 8);
#pragma unroll
        for (int mi = 0; mi < 4; ++mi)
#pragma unroll
            for (int ni = 0; ni < 4; ++ni)
                acc[mi][ni] = __builtin_amdgcn_mfma_f32_16x16x32_f16(
                    af[mi], bfr[ni], acc[mi][ni], 0, 0, 0);
        __syncthreads();
    }

    float scl[4], bs[4];
#pragma unroll
    for (int ni = 0; ni < 4; ++ni) {
        int n = n0 + wn + ni * 16 + col;
        scl[ni] = scale[n];
        bs[ni]  = bias[n];
    }
#pragma unroll
    for (int mi = 0; mi < 4; ++mi) {
#pragma unroll
        for (int rr = 0; rr < 4; ++rr) {
            int m = m0 + wm + mi * 16 + quad * 4 + rr;
            float* cp = C + (size_t)m * N_DIM + n0 + wn + col;
#pragma unroll
            for (int ni = 0; ni < 4; ++ni) {
                cp[ni * 16] = acc[mi][ni][rr] * scl[ni] + bs[ni];
            }
        }
    }
}

extern "C" void kernel_launch(void* const* d_in, const int* in_sizes, int n_in,
                              void* d_out, int out_size, void* d_ws, size_t ws_size,
                              hipStream_t stream) {
    const float* x     = (const float*)d_in[0];   // fp16 values, f32 storage
    const void*  qw    = d_in[1];                 // int32 (or raw int8) [N,K]
    const float* scale = (const float*)d_in[2];
    const float* bias  = (const float*)d_in[3];
    float* out = (float*)d_out;

    int* flag = (int*)d_ws;   // written every launch before being read

    const size_t A_BYTES = (size_t)M_DIM * K_DIM * 2;   //  67,108,864
    const size_t W_BYTES = (size_t)N_DIM * K_DIM * 2;   //  90,177,536
    const size_t NEED    = 256 + A_BYTES + W_BYTES;

    sniff_kernel<<<1, 256, 0, stream>>>((const int*)qw, flag);

    if (ws_size >= NEED) {
        _Float16* Ah = (_Float16*)((char*)d_ws + 256);
        _Float16* Wh = (_Float16*)((char*)d_ws + 256 + A_BYTES);
        cvt_x_kernel<<<2048, 256, 0, stream>>>(x, Ah);
        cvt_w_kernel<<<2048, 256, 0, stream>>>(qw, Wh, flag);
        f16_gemm_kernel<<<NWG, 256, 0, stream>>>(Ah, Wh, scale, bias, out);
    } else {
        w8_gemm_kernel<<<TM * TN, 256, 0, stream>>>(x, qw, scale, bias, out, flag);
    }
}

// Round 2
// 1260.524 us; speedup vs baseline: 1.6565x; 1.1402x over previous
//
#include <hip/hip_runtime.h>
#include <hip/hip_fp16.h>
#include <stdint.h>

// Problem constants (fixed by the reference file)
#define M_DIM 8192    // B*S = 4*2048
#define K_DIM 4096    // IN_F
#define N_DIM 11008   // OUT_F

// Harness dtype model (verified passing rounds 0-1):
//   x, scale, bias: fp16 values delivered as float32 buffers
//   qweight: int8 values delivered as int32 (sniff confirms) or raw int8
//   output: float32 buffer
// All values are exactly fp16-representable -> f16 MFMA is exact.

typedef _Float16 f16x8 __attribute__((ext_vector_type(8)));  // 8 fp16 = 4 VGPRs
typedef float f32x4 __attribute__((ext_vector_type(4)));     // MFMA 16x16 acc

typedef const void __attribute__((address_space(1)))* gptr_t;
typedef void __attribute__((address_space(3)))* lptr_t;

__device__ __forceinline__ void async_load16(const void* g, void* l) {
    // global -> LDS DMA, 16B per lane. LDS dest is wave-uniform base + lane*16
    // (we pass linear tid*16 addresses).
    __builtin_amdgcn_global_load_lds((gptr_t)g, (lptr_t)l, 16, 0, 0);
}

// Raw tile barrier: wait own staging loads (issued a full tile ago -> landed),
// publish LDS, converge. NO lgkm/exp drain, no compiler __syncthreads drain.
__device__ __forceinline__ void tile_barrier() {
    __builtin_amdgcn_sched_barrier(0);
    asm volatile("s_waitcnt vmcnt(0)" ::: "memory");
    __builtin_amdgcn_s_barrier();
    __builtin_amdgcn_sched_barrier(0);
}

// ---------------------------------------------------------------------------
// sniff: decide whether qweight arrived as int32 (harness-upcast) or raw int8.
// ---------------------------------------------------------------------------
__global__ void sniff_kernel(const int* __restrict__ q, int* __restrict__ flag) {
    __shared__ int s;
    if (threadIdx.x == 0) s = 1;
    __syncthreads();
    int bad = 0;
#pragma unroll
    for (int i = 0; i < 16; ++i) {
        int v = q[threadIdx.x * 16 + i];
        if (v < -127 || v > 127) bad = 1;
    }
    if (bad) s = 0;   // benign race: all writers write 0
    __syncthreads();
    if (threadIdx.x == 0) flag[0] = s;
}

// ---------------------------------------------------------------------------
// Convert passes: one streaming read+write each, then the GEMM runs pure f16.
// ---------------------------------------------------------------------------
__global__ __launch_bounds__(256)
void cvt_x_kernel(const float* __restrict__ in, _Float16* __restrict__ out) {
    const size_t n8 = (size_t)M_DIM * K_DIM / 8;
    const size_t stride = (size_t)gridDim.x * 256;
    for (size_t i = (size_t)blockIdx.x * 256 + threadIdx.x; i < n8; i += stride) {
        const float4* p = (const float4*)(in + i * 8);
        float4 a = p[0], b = p[1];
        f16x8 h;
        h[0] = (_Float16)a.x; h[1] = (_Float16)a.y;
        h[2] = (_Float16)a.z; h[3] = (_Float16)a.w;
        h[4] = (_Float16)b.x; h[5] = (_Float16)b.y;
        h[6] = (_Float16)b.z; h[7] = (_Float16)b.w;
        *(f16x8*)(out + i * 8) = h;
    }
}

__global__ __launch_bounds__(256)
void cvt_w_kernel(const void* __restrict__ in, _Float16* __restrict__ out,
                  const int* __restrict__ flag) {
    const bool w_is_i32 = (flag[0] != 0);              // uniform branch
    const size_t n8 = (size_t)N_DIM * K_DIM / 8;
    const size_t stride = (size_t)gridDim.x * 256;
    if (w_is_i32) {
        const int* q = (const int*)in;
        for (size_t i = (size_t)blockIdx.x * 256 + threadIdx.x; i < n8; i += stride) {
            const int4* p = (const int4*)(q + i * 8);
            int4 a = p[0], b = p[1];
            f16x8 h;
            h[0] = (_Float16)a.x; h[1] = (_Float16)a.y;
            h[2] = (_Float16)a.z; h[3] = (_Float16)a.w;
            h[4] = (_Float16)b.x; h[5] = (_Float16)b.y;
            h[6] = (_Float16)b.z; h[7] = (_Float16)b.w;
            *(f16x8*)(out + i * 8) = h;
        }
    } else {
        const signed char* q = (const signed char*)in;
        for (size_t i = (size_t)blockIdx.x * 256 + threadIdx.x; i < n8; i += stride) {
            const int2* p = (const int2*)(q + i * 8);
            int2 raw = p[0];
            f16x8 h;
            h[0] = (_Float16)(signed char)(raw.x & 0xff);
            h[1] = (_Float16)(signed char)((raw.x >> 8) & 0xff);
            h[2] = (_Float16)(signed char)((raw.x >> 16) & 0xff);
            h[3] = (_Float16)(signed char)((raw.x >> 24) & 0xff);
            h[4] = (_Float16)(signed char)(raw.y & 0xff);
            h[5] = (_Float16)(signed char)((raw.y >> 8) & 0xff);
            h[6] = (_Float16)(signed char)((raw.y >> 16) & 0xff);
            h[7] = (_Float16)(signed char)((raw.y >> 24) & 0xff);
            *(f16x8*)(out + i * 8) = h;
        }
    }
}

// ---------------------------------------------------------------------------
// Fast path: f16 x f16 GEMM, 256x256 tile, BK=64, 8 waves (2Mx4N),
// double-buffered LDS (128 KB), raw-barrier pipeline:
//   - stage tile t+1 (8x global_load_lds_dwordx4/thread) at TOP of tile t
//   - compute tile t in 4 quadrant phases (16 MFMA each, setprio-wrapped)
//   - single vmcnt(0)+s_barrier at tile END (loads had a full tile of cover)
// Race-freedom: staging only writes buf[t+1 & 1] (never the buffer being
// read); tile t-1's ds_reads all retired (lgkmcnt before their MFMA uses)
// before the end-of-(t-1) barrier, which precedes the stage that overwrites
// that buffer (issued in tile t+... at top of tile t+1).
// LDS swizzle identical to the round-1 kernel (measured 0 bank conflicts):
// LDS[row][cp] = global chunk cp ^ (row&7); linear gl_lds dest, inverse-
// swizzled global source, same XOR on ds_read (rule #21).
// ---------------------------------------------------------------------------
#define BM2 256
#define BN2 256
#define BK2 64
#define TM2 (M_DIM / BM2)   // 32
#define TN2 (N_DIM / BN2)   // 43  (256*43 = 11008 exactly)
#define NWG2 (TM2 * TN2)    // 1376 = 8 * 172 -> bijective XCD chunking

__global__ __launch_bounds__(512, 2)
void f16_gemm256_kernel(const _Float16* __restrict__ A,   // [M,K] f16
                        const _Float16* __restrict__ W,   // [N,K] f16
                        const float* __restrict__ scale,  // [N]
                        const float* __restrict__ bias,   // [N]
                        float* __restrict__ C)            // [M,N] f32
{
    __shared__ __align__(16) _Float16 As[2 * BM2 * BK2];   // 64 KB
    __shared__ __align__(16) _Float16 Bs[2 * BN2 * BK2];   // 64 KB

    const int tid  = threadIdx.x;
    const int wave = tid >> 6;
    const int lane = tid & 63;
    const int quad = lane >> 4;
    const int col  = lane & 15;

    // XCD-chunked mapping: xcd = bid%8 (HW round-robin). Each XCD owns 4
    // bm-groups x 43 bn. Consecutive r share bm -> one 2 MB A-panel stays
    // hot in the XCD's 4 MB L2 while bn sweeps; W panels stream via LLC.
    const int bid = blockIdx.x;
    const int xcd = bid & 7;
    const int r   = bid >> 3;            // 0..171
    const int bm  = xcd * 4 + r / TN2;   // 0..31
    const int bn  = r % TN2;             // 0..42

    const int m0 = bm * BM2;
    const int n0 = bn * BN2;
    const int wm = (wave >> 2) * 128;    // 2 M-waves
    const int wn = (wave & 3) * 64;      // 4 N-waves

    f32x4 acc[8][4];
#pragma unroll
    for (int i = 0; i < 8; ++i)
#pragma unroll
        for (int j = 0; j < 4; ++j)
            acc[i][j] = (f32x4){0.f, 0.f, 0.f, 0.f};

    // Staging geometry: thread t covers rows (t>>3)+64i (i=0..3), 16B chunk
    // (t&7). Global source chunk pre-XORed with row&7; LDS dest linear
    // (= row*128B + (t&7)*16B = tid*16 + i*8192 -- affine in lane).
    const int srow   = tid >> 3;                       // 0..63
    const int schunk = (tid & 7) ^ (srow & 7);
    const _Float16* ga = A + (size_t)(m0 + srow) * K_DIM + schunk * 8;
    const _Float16* gw = W + (size_t)(n0 + srow) * K_DIM + schunk * 8;

    // Fragment chunk offsets (elements): chunk (ks*4+quad) ^ (row&7), and
    // row&7 == col&7 for all fragment rows (wm, rh*64, mi*16 are mult. of 16).
    const int cx0 = ((0 * 4 + quad) ^ (col & 7)) * 8;
    const int cx1 = ((1 * 4 + quad) ^ (col & 7)) * 8;

    // ---- prologue: stage tile 0 into buf 0 ----
#pragma unroll
    for (int i = 0; i < 4; ++i) {
        async_load16(ga + (size_t)i * 64 * K_DIM, As + tid * 8 + i * 4096);
        async_load16(gw + (size_t)i * 64 * K_DIM, Bs + tid * 8 + i * 4096);
    }
    tile_barrier();

    const int NT = K_DIM / BK2;   // 64
#pragma unroll 2
    for (int t = 0; t < NT; ++t) {
        const int cur = t & 1;
        const _Float16* Ab = As + cur * (BM2 * BK2);
        const _Float16* Bb = Bs + cur * (BN2 * BK2);

        // ---- issue next-tile staging first (oldest in queue, max cover) ----
        if (t + 1 < NT) {
            const int nxt = cur ^ 1;
            const int k1 = (t + 1) * BK2;
            _Float16* la = As + nxt * (BM2 * BK2) + tid * 8;
            _Float16* lb = Bs + nxt * (BN2 * BK2) + tid * 8;
#pragma unroll
            for (int i = 0; i < 4; ++i) {
                async_load16(ga + (size_t)i * 64 * K_DIM + k1, la + i * 4096);
                async_load16(gw + (size_t)i * 64 * K_DIM + k1, lb + i * 4096);
            }
        }

        f16x8 a[8], bq[8];
        // ---- phase 1: A rows wm..wm+63, B cols wn..wn+31 ----
#pragma unroll
        for (int mi = 0; mi < 4; ++mi) {
            const _Float16* ap = Ab + (wm + mi * 16 + col) * BK2;
            a[mi * 2 + 0] = *(const f16x8*)(ap + cx0);
            a[mi * 2 + 1] = *(const f16x8*)(ap + cx1);
        }
#pragma unroll
        for (int ni = 0; ni < 2; ++ni) {
            const _Float16* bp = Bb + (wn + ni * 16 + col) * BK2;
            bq[ni * 2 + 0] = *(const f16x8*)(bp + cx0);
            bq[ni * 2 + 1] = *(const f16x8*)(bp + cx1);
        }
        __builtin_amdgcn_s_setprio(1);
#pragma unroll
        for (int mi = 0; mi < 4; ++mi)
#pragma unroll
            for (int ni = 0; ni < 2; ++ni) {
                acc[mi][ni] = __builtin_amdgcn_mfma_f32_16x16x32_f16(
                    a[mi * 2 + 0], bq[ni * 2 + 0], acc[mi][ni], 0, 0, 0);
                acc[mi][ni] = __builtin_amdgcn_mfma_f32_16x16x32_f16(
                    a[mi * 2 + 1], bq[ni * 2 + 1], acc[mi][ni], 0, 0, 0);
            }
        __builtin_amdgcn_s_setprio(0);

        // ---- phase 2: same A rows, B cols wn+32..wn+63 ----
#pragma unroll
        for (int ni = 2; ni < 4; ++ni) {
            const _Float16* bp = Bb + (wn + ni * 16 + col) * BK2;
            bq[ni * 2 + 0] = *(const f16x8*)(bp + cx0);
            bq[ni * 2 + 1] = *(const f16x8*)(bp + cx1);
        }
        __builtin_amdgcn_s_setprio(1);
#pragma unroll
        for (int mi = 0; mi < 4; ++mi)
#pragma unroll
            for (int ni = 2; ni < 4; ++ni) {
                acc[mi][ni] = __builtin_amdgcn_mfma_f32_16x16x32_f16(
                    a[mi * 2 + 0], bq[ni * 2 + 0], acc[mi][ni], 0, 0, 0);
                acc[mi][ni] = __builtin_amdgcn_mfma_f32_16x16x32_f16(
                    a[mi * 2 + 1], bq[ni * 2 + 1], acc[mi][ni], 0, 0, 0);
            }
        __builtin_amdgcn_s_setprio(0);

        // ---- phase 3: A rows wm+64..wm+127, B cols wn..wn+31 (regs) ----
#pragma unroll
        for (int mi = 0; mi < 4; ++mi) {
            const _Float16* ap = Ab + (wm + 64 + mi * 16 + col) * BK2;
            a[mi * 2 + 0] = *(const f16x8*)(ap + cx0);
            a[mi * 2 + 1] = *(const f16x8*)(ap + cx1);
        }
        __builtin_amdgcn_s_setprio(1);
#pragma unroll
        for (int mi = 0; mi < 4; ++mi)
#pragma unroll
            for (int ni = 0; ni < 2; ++ni) {
                acc[4 + mi][ni] = __builtin_amdgcn_mfma_f32_16x16x32_f16(
                    a[mi * 2 + 0], bq[ni * 2 + 0], acc[4 + mi][ni], 0, 0, 0);
                acc[4 + mi][ni] = __builtin_amdgcn_mfma_f32_16x16x32_f16(
                    a[mi * 2 + 1], bq[ni * 2 + 1], acc[4 + mi][ni], 0, 0, 0);
            }
        __builtin_amdgcn_s_setprio(0);

        // ---- phase 4: A rows wm+64.., B cols wn+32.. (all regs) ----
        __builtin_amdgcn_s_setprio(1);
#pragma unroll
        for (int mi = 0; mi < 4; ++mi)
#pragma unroll
            for (int ni = 2; ni < 4; ++ni) {
                acc[4 + mi][ni] = __builtin_amdgcn_mfma_f32_16x16x32_f16(
                    a[mi * 2 + 0], bq[ni * 2 + 0], acc[4 + mi][ni], 0, 0, 0);
                acc[4 + mi][ni] = __builtin_amdgcn_mfma_f32_16x16x32_f16(
                    a[mi * 2 + 1], bq[ni * 2 + 1], acc[4 + mi][ni], 0, 0, 0);
            }
        __builtin_amdgcn_s_setprio(0);

        // ---- publish next buffer / converge ----
        tile_barrier();
    }

    // ---- epilogue: C/D map col=lane&15, row=quad*4+reg (m89-verified) ----
    float scl[4], bsv[4];
#pragma unroll
    for (int ni = 0; ni < 4; ++ni) {
        int n = n0 + wn + ni * 16 + col;
        scl[ni] = scale[n];
        bsv[ni] = bias[n];
    }
#pragma unroll
    for (int rh = 0; rh < 2; ++rh) {
#pragma unroll
        for (int mi = 0; mi < 4; ++mi) {
#pragma unroll
            for (int rr = 0; rr < 4; ++rr) {
                int m = m0 + wm + rh * 64 + mi * 16 + quad * 4 + rr;
                float* cp = C + (size_t)m * N_DIM + n0 + wn + col;
#pragma unroll
                for (int ni = 0; ni < 4; ++ni) {
                    cp[ni * 16] = acc[rh * 4 + mi][ni][rr] * scl[ni] + bsv[ni];
                }
            }
        }
    }
}

// ---------------------------------------------------------------------------
// Fallback (workspace too small): round-0 verified kernel, unchanged.
// ---------------------------------------------------------------------------
#define BM 128
#define BN 128
#define OBK 32
#define TM (M_DIM / BM)   // 64
#define TN (N_DIM / BN)   // 86

__global__ __launch_bounds__(256)
void w8_gemm_kernel(const float* __restrict__ A,
                    const void* __restrict__ Wv,
                    const float* __restrict__ scale,
                    const float* __restrict__ bias,
                    float* __restrict__ C,
                    const int* __restrict__ flag)
{
    __shared__ __align__(16) _Float16 As[BM * OBK];
    __shared__ __align__(16) _Float16 Bs[BN * OBK];

    const int tid  = threadIdx.x;
    const int wave = tid >> 6;
    const int lane = tid & 63;
    const int quad = lane >> 4;
    const int col  = lane & 15;

    const bool w_is_i32 = (flag[0] != 0);

    int bid = blockIdx.x;
    const int per_group = 8 * TN;
    int g = bid / per_group;
    int r = bid - g * per_group;
    const int bm = g * 8 + (r & 7);
    const int bn = r >> 3;

    const int m0 = bm * BM;
    const int n0 = bn * BN;
    const int wm = (wave >> 1) * 64;
    const int wn = (wave & 1) * 64;

    f32x4 acc[4][4];
#pragma unroll
    for (int mi = 0; mi < 4; ++mi)
#pragma unroll
        for (int ni = 0; ni < 4; ++ni)
            acc[mi][ni] = (f32x4){0.f, 0.f, 0.f, 0.f};

    for (int k0 = 0; k0 < K_DIM; k0 += OBK) {
#pragma unroll
        for (int i = 0; i < 2; ++i) {
            int idx = i * 256 + tid;
            int row = idx >> 2;
            int c   = idx & 3;
            const float4* p = (const float4*)(A + (size_t)(m0 + row) * K_DIM + k0 + c * 8);
            float4 v0 = p[0];
            float4 v1 = p[1];
            f16x8 h;
            h[0] = (_Float16)v0.x; h[1] = (_Float16)v0.y;
            h[2] = (_Float16)v0.z; h[3] = (_Float16)v0.w;
            h[4] = (_Float16)v1.x; h[5] = (_Float16)v1.y;
            h[6] = (_Float16)v1.z; h[7] = (_Float16)v1.w;
            *(f16x8*)(As + idx * 8) = h;
        }
        if (w_is_i32) {
            const int* Wq = (const int*)Wv;
#pragma unroll
            for (int i = 0; i < 2; ++i) {
                int idx = i * 256 + tid;
                int row = idx >> 2;
                int c   = idx & 3;
                const int4* p = (const int4*)(Wq + (size_t)(n0 + row) * K_DIM + k0 + c * 8);
                int4 a = p[0];
                int4 b = p[1];
                f16x8 h;
                h[0] = (_Float16)a.x; h[1] = (_Float16)a.y;
                h[2] = (_Float16)a.z; h[3] = (_Float16)a.w;
                h[4] = (_Float16)b.x; h[5] = (_Float16)b.y;
                h[6] = (_Float16)b.z; h[7] = (_Float16)b.w;
                *(f16x8*)(Bs + idx * 8) = h;
            }
        } else {
            const signed char* W8 = (const signed char*)Wv;
#pragma unroll
            for (int i = 0; i < 2; ++i) {
                int idx = i * 256 + tid;
                int row = idx >> 2;
                int c   = idx & 3;
                const int2* p = (const int2*)(W8 + (size_t)(n0 + row) * K_DIM + k0 + c * 8);
                int2 raw = p[0];
                f16x8 h;
                h[0] = (_Float16)(signed char)(raw.x & 0xff);
                h[1] = (_Float16)(signed char)((raw.x >> 8) & 0xff);
                h[2] = (_Float16)(signed char)((raw.x >> 16) & 0xff);
                h[3] = (_Float16)(signed char)((raw.x >> 24) & 0xff);
                h[4] = (_Float16)(signed char)(raw.y & 0xff);
                h[5] = (_Float16)(signed char)((raw.y >> 8) & 0xff);
                h[6] = (_Float16)(signed char)((raw.y >> 16) & 0xff);
                h[7] = (_Float16)(signed char)((raw.y >> 24) & 0xff);
                *(f16x8*)(Bs + idx * 8) = h;
            }
        }
        __syncthreads();

        f16x8 af[4], bfr[4];
#pragma unroll
        for (int mi = 0; mi < 4; ++mi)
            af[mi] = *(const f16x8*)(As + (wm + mi * 16 + col) * OBK + quad * 8);
#pragma unroll
        for (int ni = 0; ni < 4; ++ni)
            bfr[ni] = *(const f16x8*)(Bs + (wn + ni * 16 + col) * OBK + quad * 8);
#pragma unroll
        for (int mi = 0; mi < 4; ++mi)
#pragma unroll
            for (int ni = 0; ni < 4; ++ni)
                acc[mi][ni] = __builtin_amdgcn_mfma_f32_16x16x32_f16(
                    af[mi], bfr[ni], acc[mi][ni], 0, 0, 0);
        __syncthreads();
    }

    float scl[4], bs[4];
#pragma unroll
    for (int ni = 0; ni < 4; ++ni) {
        int n = n0 + wn + ni * 16 + col;
        scl[ni] = scale[n];
        bs[ni]  = bias[n];
    }
#pragma unroll
    for (int mi = 0; mi < 4; ++mi) {
#pragma unroll
        for (int rr = 0; rr < 4; ++rr) {
            int m = m0 + wm + mi * 16 + quad * 4 + rr;
            float* cp = C + (size_t)m * N_DIM + n0 + wn + col;
#pragma unroll
            for (int ni = 0; ni < 4; ++ni) {
                cp[ni * 16] = acc[mi][ni][rr] * scl[ni] + bs[ni];
            }
        }
    }
}

extern "C" void kernel_launch(void* const* d_in, const int* in_sizes, int n_in,
                              void* d_out, int out_size, void* d_ws, size_t ws_size,
                              hipStream_t stream) {
    const float* x     = (const float*)d_in[0];   // fp16 values, f32 storage
    const void*  qw    = d_in[1];                 // int32 (or raw int8) [N,K]
    const float* scale = (const float*)d_in[2];
    const float* bias  = (const float*)d_in[3];
    float* out = (float*)d_out;

    int* flag = (int*)d_ws;   // written every launch before being read

    const size_t A_BYTES = (size_t)M_DIM * K_DIM * 2;   //  67,108,864
    const size_t W_BYTES = (size_t)N_DIM * K_DIM * 2;   //  90,177,536
    const size_t NEED    = 256 + A_BYTES + W_BYTES;

    sniff_kernel<<<1, 256, 0, stream>>>((const int*)qw, flag);

    if (ws_size >= NEED) {
        _Float16* Ah = (_Float16*)((char*)d_ws + 256);
        _Float16* Wh = (_Float16*)((char*)d_ws + 256 + A_BYTES);
        cvt_x_kernel<<<2048, 256, 0, stream>>>(x, Ah);
        cvt_w_kernel<<<2048, 256, 0, stream>>>(qw, Wh, flag);
        f16_gemm256_kernel<<<NWG2, 512, 0, stream>>>(Ah, Wh, scale, bias, out);
    } else {
        w8_gemm_kernel<<<TM * TN, 256, 0, stream>>>(x, qw, scale, bias, out, flag);
    }
}

// Round 3
// 1241.660 us; speedup vs baseline: 1.6816x; 1.0152x over previous
//
#include <hip/hip_runtime.h>
#include <hip/hip_fp16.h>
#include <stdint.h>

// Problem constants (fixed by the reference file)
#define M_DIM 8192    // B*S = 4*2048
#define K_DIM 4096    // IN_F
#define N_DIM 11008   // OUT_F

// Harness dtype model (verified passing rounds 0-2):
//   x, scale, bias: fp16 values delivered as float32 buffers
//   qweight: int8 values delivered as int32 (sniff confirms) or raw int8
//   output: float32 buffer
// All values are exactly fp16-representable -> f16 MFMA is exact.

typedef _Float16 f16x8 __attribute__((ext_vector_type(8)));  // 8 fp16 = 4 VGPRs
typedef float f32x4 __attribute__((ext_vector_type(4)));     // MFMA 16x16 acc

typedef const void __attribute__((address_space(1)))* gptr_t;
typedef void __attribute__((address_space(3)))* lptr_t;

__device__ __forceinline__ void async_load16(const void* g, void* l) {
    // global -> LDS DMA, 16B per lane. LDS dest is wave-uniform base + lane*16
    // (all staging dests below are affine in lane with stride 16B).
    __builtin_amdgcn_global_load_lds((gptr_t)g, (lptr_t)l, 16, 0, 0);
}

// Counted-wait barrier: oldest loads beyond 4 have landed; publish; converge.
// The queue NEVER drains to 0 in the main loop (T4, m218).
__device__ __forceinline__ void wait4_barrier() {
    __builtin_amdgcn_sched_barrier(0);
    asm volatile("s_waitcnt vmcnt(4)" ::: "memory");
    __builtin_amdgcn_s_barrier();
    __builtin_amdgcn_sched_barrier(0);
}
__device__ __forceinline__ void plain_barrier() {
    __builtin_amdgcn_sched_barrier(0);
    asm volatile("" ::: "memory");
    __builtin_amdgcn_s_barrier();
    __builtin_amdgcn_sched_barrier(0);
}

// ---------------------------------------------------------------------------
// sniff: decide whether qweight arrived as int32 (harness-upcast) or raw int8.
// ---------------------------------------------------------------------------
__global__ void sniff_kernel(const int* __restrict__ q, int* __restrict__ flag) {
    __shared__ int s;
    if (threadIdx.x == 0) s = 1;
    __syncthreads();
    int bad = 0;
#pragma unroll
    for (int i = 0; i < 16; ++i) {
        int v = q[threadIdx.x * 16 + i];
        if (v < -127 || v > 127) bad = 1;
    }
    if (bad) s = 0;   // benign race: all writers write 0
    __syncthreads();
    if (threadIdx.x == 0) flag[0] = s;
}

// ---------------------------------------------------------------------------
// Convert passes: one streaming read+write each, then the GEMM runs pure f16.
// ---------------------------------------------------------------------------
__global__ __launch_bounds__(256)
void cvt_x_kernel(const float* __restrict__ in, _Float16* __restrict__ out) {
    const size_t n8 = (size_t)M_DIM * K_DIM / 8;
    const size_t stride = (size_t)gridDim.x * 256;
    for (size_t i = (size_t)blockIdx.x * 256 + threadIdx.x; i < n8; i += stride) {
        const float4* p = (const float4*)(in + i * 8);
        float4 a = p[0], b = p[1];
        f16x8 h;
        h[0] = (_Float16)a.x; h[1] = (_Float16)a.y;
        h[2] = (_Float16)a.z; h[3] = (_Float16)a.w;
        h[4] = (_Float16)b.x; h[5] = (_Float16)b.y;
        h[6] = (_Float16)b.z; h[7] = (_Float16)b.w;
        *(f16x8*)(out + i * 8) = h;
    }
}

__global__ __launch_bounds__(256)
void cvt_w_kernel(const void* __restrict__ in, _Float16* __restrict__ out,
                  const int* __restrict__ flag) {
    const bool w_is_i32 = (flag[0] != 0);              // uniform branch
    const size_t n8 = (size_t)N_DIM * K_DIM / 8;
    const size_t stride = (size_t)gridDim.x * 256;
    if (w_is_i32) {
        const int* q = (const int*)in;
        for (size_t i = (size_t)blockIdx.x * 256 + threadIdx.x; i < n8; i += stride) {
            const int4* p = (const int4*)(q + i * 8);
            int4 a = p[0], b = p[1];
            f16x8 h;
            h[0] = (_Float16)a.x; h[1] = (_Float16)a.y;
            h[2] = (_Float16)a.z; h[3] = (_Float16)a.w;
            h[4] = (_Float16)b.x; h[5] = (_Float16)b.y;
            h[6] = (_Float16)b.z; h[7] = (_Float16)b.w;
            *(f16x8*)(out + i * 8) = h;
        }
    } else {
        const signed char* q = (const signed char*)in;
        for (size_t i = (size_t)blockIdx.x * 256 + threadIdx.x; i < n8; i += stride) {
            const int2* p = (const int2*)(q + i * 8);
            int2 raw = p[0];
            f16x8 h;
            h[0] = (_Float16)(signed char)(raw.x & 0xff);
            h[1] = (_Float16)(signed char)((raw.x >> 8) & 0xff);
            h[2] = (_Float16)(signed char)((raw.x >> 16) & 0xff);
            h[3] = (_Float16)(signed char)((raw.x >> 24) & 0xff);
            h[4] = (_Float16)(signed char)(raw.y & 0xff);
            h[5] = (_Float16)(signed char)((raw.y >> 8) & 0xff);
            h[6] = (_Float16)(signed char)((raw.y >> 16) & 0xff);
            h[7] = (_Float16)(signed char)((raw.y >> 24) & 0xff);
            *(f16x8*)(out + i * 8) = h;
        }
    }
}

// ---------------------------------------------------------------------------
// Fast path: f16 x f16 GEMM, 256x256 tile, BK=64, 8 waves (2Mx4N), 128 KB
// double-buffered LDS, 4-phase counted-vmcnt pipeline (T3+T4+T5):
//
// Staging groups per K-tile (2 gl_lds/thread each, issue order = FIFO order):
//   GAa = A rows {0-63,128-191}   (what ALL waves' P1/P2 A-frags read)
//   GBa = B rows {p*64+0..31}     (ALL waves' P1 B-frags)
//   GBb = B rows {p*64+32..63}    (P2 B-frags)
//   GAb = A rows {64-127,192-255} (P3/P4 A-frags)
// Tile t issues groups for t+1 at phases P1..P4. FIFO vmcnt arithmetic:
//   end-P1: queue=[GBb(t),GAb(t),GAa(t+1)]=6 -> vmcnt(4) covers GBb(t) (P2)
//   end-P2: queue=[GAb(t),GAa',GBa']=6       -> vmcnt(4) covers GAb(t) (P3)
//   end-P3: no wait
//   end-P4: queue=[GAa',GBa',GBb',GAb']=8    -> vmcnt(4) covers GAa',GBa' (P1')
// Queue oscillates 4..8, never drains. Staged rows are disjoint from rows
// concurrently read (checked per group), so in-flight arrivals are race-free.
// Last tile wraps prefetch to k=0 (harmless) to keep counts uniform.
// LDS swizzle identical to rounds 1-2 (0 conflicts measured): linear gl_lds
// dest, inverse-XOR global source, same XOR on ds_read (rule #21).
// ---------------------------------------------------------------------------
#define BM2 256
#define BN2 256
#define BK2 64
#define TM2 (M_DIM / BM2)   // 32
#define TN2 (N_DIM / BN2)   // 43  (256*43 = 11008 exactly)
#define NWG2 (TM2 * TN2)    // 1376 = 8 * 172 -> bijective XCD chunking
#define BUFE (BM2 * BK2)    // 16384 f16 per buffer

__global__ __launch_bounds__(512, 2)
void f16_gemm256_kernel(const _Float16* __restrict__ A,   // [M,K] f16
                        const _Float16* __restrict__ W,   // [N,K] f16
                        const float* __restrict__ scale,  // [N]
                        const float* __restrict__ bias,   // [N]
                        float* __restrict__ C)            // [M,N] f32
{
    __shared__ __align__(16) _Float16 As[2 * BUFE];   // 64 KB
    __shared__ __align__(16) _Float16 Bs[2 * BUFE];   // 64 KB

    const int tid  = threadIdx.x;
    const int wave = tid >> 6;
    const int lane = tid & 63;
    const int quad = lane >> 4;
    const int col  = lane & 15;

    // XCD-chunked mapping (verified: FETCH ~1.5 GB, near-minimal).
    const int bid = blockIdx.x;
    const int xcd = bid & 7;
    const int r   = bid >> 3;            // 0..171
    const int bm  = xcd * 4 + r / TN2;   // 0..31
    const int bn  = r % TN2;             // 0..42

    const int m0 = bm * BM2;
    const int n0 = bn * BN2;
    const int wm = (wave >> 2) * 128;    // 2 M-waves
    const int wn = (wave & 3) * 64;      // 4 N-waves

    f32x4 acc[8][4];
#pragma unroll
    for (int i = 0; i < 8; ++i)
#pragma unroll
        for (int j = 0; j < 4; ++j)
            acc[i][j] = (f32x4){0.f, 0.f, 0.f, 0.f};

    // Staging geometry. tq = thread's base row slot, chunk slot = tid&7.
    // Global chunk pre-XORed with row&7 (== tq&7 for every staged row, since
    // all row offsets are multiples of 8); LDS dest linear per (wave, load).
    const int tq     = tid >> 3;                       // 0..63
    const int c8     = (tid & 7) * 8;                  // LDS chunk offset (f16)
    const int schunk = (tid & 7) ^ (tq & 7);
    const _Float16* gA = A + (size_t)(m0 + tq) * K_DIM + schunk * 8;
    const int br0 = ((tq >> 5) << 6) + (tq & 31);      // B alpha base row
    const _Float16* gB = W + (size_t)(n0 + br0) * K_DIM + schunk * 8;
    const int la0 = tid * 8;                           // A row tq dest (f16)
    const int lb0 = br0 * 64 + c8;                     // B row br0 dest

    // Fragment chunk offsets: chunk (ks*4+quad) ^ (col&7); frag row&7 == col&7.
    const int cx0 = ((0 * 4 + quad) ^ (col & 7)) * 8;
    const int cx1 = ((1 * 4 + quad) ^ (col & 7)) * 8;

    // ---- prologue: stage tile 0 into buf 0 (order GAa, GBa, GBb, GAb) ----
    {
        _Float16* An = As;
        _Float16* Bn = Bs;
        async_load16(gA,                            An + la0);
        async_load16(gA + (size_t)128 * K_DIM,      An + 8192 + la0);
        async_load16(gB,                            Bn + lb0);
        async_load16(gB + (size_t)128 * K_DIM,      Bn + 8192 + lb0);
        async_load16(gB + (size_t)32 * K_DIM,       Bn + 2048 + lb0);
        async_load16(gB + (size_t)160 * K_DIM,      Bn + 10240 + lb0);
        async_load16(gA + (size_t)64 * K_DIM,       An + 4096 + la0);
        async_load16(gA + (size_t)192 * K_DIM,      An + 12288 + la0);
    }
    wait4_barrier();   // GAa(0), GBa(0) landed -> P1 of tile 0 safe

    const int NT = K_DIM / BK2;   // 64
#pragma unroll 2
    for (int t = 0; t < NT; ++t) {
        const int cur = t & 1;
        const _Float16* Ab = As + cur * BUFE;
        const _Float16* Bb = Bs + cur * BUFE;
        _Float16* An = As + (cur ^ 1) * BUFE;
        _Float16* Bn = Bs + (cur ^ 1) * BUFE;
        const int kk = ((t + 1) & (NT - 1)) * BK2;   // wrap keeps counts uniform

        f16x8 alo[8], ba[4], bb[4], ahi[8];

        // ---- P1: issue GAa(t+1); read A-lo + B-a; MFMA q1 ----
        async_load16(gA + kk,                       An + la0);
        async_load16(gA + (size_t)128 * K_DIM + kk, An + 8192 + la0);
#pragma unroll
        for (int mi = 0; mi < 4; ++mi) {
            const _Float16* ap = Ab + (wm + mi * 16 + col) * BK2;
            alo[mi * 2 + 0] = *(const f16x8*)(ap + cx0);
            alo[mi * 2 + 1] = *(const f16x8*)(ap + cx1);
        }
#pragma unroll
        for (int ni = 0; ni < 2; ++ni) {
            const _Float16* bp = Bb + (wn + ni * 16 + col) * BK2;
            ba[ni * 2 + 0] = *(const f16x8*)(bp + cx0);
            ba[ni * 2 + 1] = *(const f16x8*)(bp + cx1);
        }
        __builtin_amdgcn_s_setprio(1);
#pragma unroll
        for (int mi = 0; mi < 4; ++mi)
#pragma unroll
            for (int ni = 0; ni < 2; ++ni) {
                acc[mi][ni] = __builtin_amdgcn_mfma_f32_16x16x32_f16(
                    alo[mi * 2 + 0], ba[ni * 2 + 0], acc[mi][ni], 0, 0, 0);
                acc[mi][ni] = __builtin_amdgcn_mfma_f32_16x16x32_f16(
                    alo[mi * 2 + 1], ba[ni * 2 + 1], acc[mi][ni], 0, 0, 0);
            }
        __builtin_amdgcn_s_setprio(0);
        wait4_barrier();   // covers GBb(t) -> P2 reads safe

        // ---- P2: issue GBa(t+1); read B-b; MFMA q2 ----
        async_load16(gB + kk,                       Bn + lb0);
        async_load16(gB + (size_t)128 * K_DIM + kk, Bn + 8192 + lb0);
#pragma unroll
        for (int ni = 0; ni < 2; ++ni) {
            const _Float16* bp = Bb + (wn + 32 + ni * 16 + col) * BK2;
            bb[ni * 2 + 0] = *(const f16x8*)(bp + cx0);
            bb[ni * 2 + 1] = *(const f16x8*)(bp + cx1);
        }
        __builtin_amdgcn_s_setprio(1);
#pragma unroll
        for (int mi = 0; mi < 4; ++mi)
#pragma unroll
            for (int ni = 0; ni < 2; ++ni) {
                acc[mi][2 + ni] = __builtin_amdgcn_mfma_f32_16x16x32_f16(
                    alo[mi * 2 + 0], bb[ni * 2 + 0], acc[mi][2 + ni], 0, 0, 0);
                acc[mi][2 + ni] = __builtin_amdgcn_mfma_f32_16x16x32_f16(
                    alo[mi * 2 + 1], bb[ni * 2 + 1], acc[mi][2 + ni], 0, 0, 0);
            }
        __builtin_amdgcn_s_setprio(0);
        wait4_barrier();   // covers GAb(t) -> P3 reads safe

        // ---- P3: issue GBb(t+1); read A-hi; MFMA q3 ----
        async_load16(gB + (size_t)32 * K_DIM + kk,  Bn + 2048 + lb0);
        async_load16(gB + (size_t)160 * K_DIM + kk, Bn + 10240 + lb0);
#pragma unroll
        for (int mi = 0; mi < 4; ++mi) {
            const _Float16* ap = Ab + (wm + 64 + mi * 16 + col) * BK2;
            ahi[mi * 2 + 0] = *(const f16x8*)(ap + cx0);
            ahi[mi * 2 + 1] = *(const f16x8*)(ap + cx1);
        }
        __builtin_amdgcn_s_setprio(1);
#pragma unroll
        for (int mi = 0; mi < 4; ++mi)
#pragma unroll
            for (int ni = 0; ni < 2; ++ni) {
                acc[4 + mi][ni] = __builtin_amdgcn_mfma_f32_16x16x32_f16(
                    ahi[mi * 2 + 0], ba[ni * 2 + 0], acc[4 + mi][ni], 0, 0, 0);
                acc[4 + mi][ni] = __builtin_amdgcn_mfma_f32_16x16x32_f16(
                    ahi[mi * 2 + 1], ba[ni * 2 + 1], acc[4 + mi][ni], 0, 0, 0);
            }
        __builtin_amdgcn_s_setprio(0);
        plain_barrier();   // no wait needed here

        // ---- P4: issue GAb(t+1); MFMA q4 (all regs) ----
        async_load16(gA + (size_t)64 * K_DIM + kk,  An + 4096 + la0);
        async_load16(gA + (size_t)192 * K_DIM + kk, An + 12288 + la0);
        __builtin_amdgcn_s_setprio(1);
#pragma unroll
        for (int mi = 0; mi < 4; ++mi)
#pragma unroll
            for (int ni = 0; ni < 2; ++ni) {
                acc[4 + mi][2 + ni] = __builtin_amdgcn_mfma_f32_16x16x32_f16(
                    ahi[mi * 2 + 0], bb[ni * 2 + 0], acc[4 + mi][2 + ni], 0, 0, 0);
                acc[4 + mi][2 + ni] = __builtin_amdgcn_mfma_f32_16x16x32_f16(
                    ahi[mi * 2 + 1], bb[ni * 2 + 1], acc[4 + mi][2 + ni], 0, 0, 0);
            }
        __builtin_amdgcn_s_setprio(0);
        wait4_barrier();   // covers GAa(t+1), GBa(t+1) -> next P1 safe
    }
    asm volatile("s_waitcnt vmcnt(0)" ::: "memory");   // drain wrap prefetch

    // ---- epilogue: C/D map col=lane&15, row=quad*4+reg (m89-verified) ----
    float scl[4], bsv[4];
#pragma unroll
    for (int ni = 0; ni < 4; ++ni) {
        int n = n0 + wn + ni * 16 + col;
        scl[ni] = scale[n];
        bsv[ni] = bias[n];
    }
#pragma unroll
    for (int rh = 0; rh < 2; ++rh) {
#pragma unroll
        for (int mi = 0; mi < 4; ++mi) {
#pragma unroll
            for (int rr = 0; rr < 4; ++rr) {
                int m = m0 + wm + rh * 64 + mi * 16 + quad * 4 + rr;
                float* cp = C + (size_t)m * N_DIM + n0 + wn + col;
#pragma unroll
                for (int ni = 0; ni < 4; ++ni) {
                    cp[ni * 16] = acc[rh * 4 + mi][ni][rr] * scl[ni] + bsv[ni];
                }
            }
        }
    }
}

// ---------------------------------------------------------------------------
// Fallback (workspace too small): round-0 verified kernel, unchanged.
// ---------------------------------------------------------------------------
#define BM 128
#define BN 128
#define OBK 32
#define TM (M_DIM / BM)   // 64
#define TN (N_DIM / BN)   // 86

__global__ __launch_bounds__(256)
void w8_gemm_kernel(const float* __restrict__ A,
                    const void* __restrict__ Wv,
                    const float* __restrict__ scale,
                    const float* __restrict__ bias,
                    float* __restrict__ C,
                    const int* __restrict__ flag)
{
    __shared__ __align__(16) _Float16 As[BM * OBK];
    __shared__ __align__(16) _Float16 Bs[BN * OBK];

    const int tid  = threadIdx.x;
    const int wave = tid >> 6;
    const int lane = tid & 63;
    const int quad = lane >> 4;
    const int col  = lane & 15;

    const bool w_is_i32 = (flag[0] != 0);

    int bid = blockIdx.x;
    const int per_group = 8 * TN;
    int g = bid / per_group;
    int r = bid - g * per_group;
    const int bm = g * 8 + (r & 7);
    const int bn = r >> 3;

    const int m0 = bm * BM;
    const int n0 = bn * BN;
    const int wm = (wave >> 1) * 64;
    const int wn = (wave & 1) * 64;

    f32x4 acc[4][4];
#pragma unroll
    for (int mi = 0; mi < 4; ++mi)
#pragma unroll
        for (int ni = 0; ni < 4; ++ni)
            acc[mi][ni] = (f32x4){0.f, 0.f, 0.f, 0.f};

    for (int k0 = 0; k0 < K_DIM; k0 += OBK) {
#pragma unroll
        for (int i = 0; i < 2; ++i) {
            int idx = i * 256 + tid;
            int row = idx >> 2;
            int c   = idx & 3;
            const float4* p = (const float4*)(A + (size_t)(m0 + row) * K_DIM + k0 + c * 8);
            float4 v0 = p[0];
            float4 v1 = p[1];
            f16x8 h;
            h[0] = (_Float16)v0.x; h[1] = (_Float16)v0.y;
            h[2] = (_Float16)v0.z; h[3] = (_Float16)v0.w;
            h[4] = (_Float16)v1.x; h[5] = (_Float16)v1.y;
            h[6] = (_Float16)v1.z; h[7] = (_Float16)v1.w;
            *(f16x8*)(As + idx * 8) = h;
        }
        if (w_is_i32) {
            const int* Wq = (const int*)Wv;
#pragma unroll
            for (int i = 0; i < 2; ++i) {
                int idx = i * 256 + tid;
                int row = idx >> 2;
                int c   = idx & 3;
                const int4* p = (const int4*)(Wq + (size_t)(n0 + row) * K_DIM + k0 + c * 8);
                int4 a = p[0];
                int4 b = p[1];
                f16x8 h;
                h[0] = (_Float16)a.x; h[1] = (_Float16)a.y;
                h[2] = (_Float16)a.z; h[3] = (_Float16)a.w;
                h[4] = (_Float16)b.x; h[5] = (_Float16)b.y;
                h[6] = (_Float16)b.z; h[7] = (_Float16)b.w;
                *(f16x8*)(Bs + idx * 8) = h;
            }
        } else {
            const signed char* W8 = (const signed char*)Wv;
#pragma unroll
            for (int i = 0; i < 2; ++i) {
                int idx = i * 256 + tid;
                int row = idx >> 2;
                int c   = idx & 3;
                const int2* p = (const int2*)(W8 + (size_t)(n0 + row) * K_DIM + k0 + c * 8);
                int2 raw = p[0];
                f16x8 h;
                h[0] = (_Float16)(signed char)(raw.x & 0xff);
                h[1] = (_Float16)(signed char)((raw.x >> 8) & 0xff);
                h[2] = (_Float16)(signed char)((raw.x >> 16) & 0xff);
                h[3] = (_Float16)(signed char)((raw.x >> 24) & 0xff);
                h[4] = (_Float16)(signed char)(raw.y & 0xff);
                h[5] = (_Float16)(signed char)((raw.y >> 8) & 0xff);
                h[6] = (_Float16)(signed char)((raw.y >> 16) & 0xff);
                h[7] = (_Float16)(signed char)((raw.y >> 24) & 0xff);
                *(f16x8*)(Bs + idx * 8) = h;
            }
        }
        __syncthreads();

        f16x8 af[4], bfr[4];
#pragma unroll
        for (int mi = 0; mi < 4; ++mi)
            af[mi] = *(const f16x8*)(As + (wm + mi * 16 + col) * OBK + quad * 8);
#pragma unroll
        for (int ni = 0; ni < 4; ++ni)
            bfr[ni] = *(const f16x8*)(Bs + (wn + ni * 16 + col) * OBK + quad * 8);
#pragma unroll
        for (int mi = 0; mi < 4; ++mi)
#pragma unroll
            for (int ni = 0; ni < 4; ++ni)
                acc[mi][ni] = __builtin_amdgcn_mfma_f32_16x16x32_f16(
                    af[mi], bfr[ni], acc[mi][ni], 0, 0, 0);
        __syncthreads();
    }

    float scl[4], bs[4];
#pragma unroll
    for (int ni = 0; ni < 4; ++ni) {
        int n = n0 + wn + ni * 16 + col;
        scl[ni] = scale[n];
        bs[ni]  = bias[n];
    }
#pragma unroll
    for (int mi = 0; mi < 4; ++mi) {
#pragma unroll
        for (int rr = 0; rr < 4; ++rr) {
            int m = m0 + wm + mi * 16 + quad * 4 + rr;
            float* cp = C + (size_t)m * N_DIM + n0 + wn + col;
#pragma unroll
            for (int ni = 0; ni < 4; ++ni) {
                cp[ni * 16] = acc[mi][ni][rr] * scl[ni] + bs[ni];
            }
        }
    }
}

extern "C" void kernel_launch(void* const* d_in, const int* in_sizes, int n_in,
                              void* d_out, int out_size, void* d_ws, size_t ws_size,
                              hipStream_t stream) {
    const float* x     = (const float*)d_in[0];   // fp16 values, f32 storage
    const void*  qw    = d_in[1];                 // int32 (or raw int8) [N,K]
    const float* scale = (const float*)d_in[2];
    const float* bias  = (const float*)d_in[3];
    float* out = (float*)d_out;

    int* flag = (int*)d_ws;   // written every launch before being read

    const size_t A_BYTES = (size_t)M_DIM * K_DIM * 2;   //  67,108,864
    const size_t W_BYTES = (size_t)N_DIM * K_DIM * 2;   //  90,177,536
    const size_t NEED    = 256 + A_BYTES + W_BYTES;

    sniff_kernel<<<1, 256, 0, stream>>>((const int*)qw, flag);

    if (ws_size >= NEED) {
        _Float16* Ah = (_Float16*)((char*)d_ws + 256);
        _Float16* Wh = (_Float16*)((char*)d_ws + 256 + A_BYTES);
        cvt_x_kernel<<<2048, 256, 0, stream>>>(x, Ah);
        cvt_w_kernel<<<2048, 256, 0, stream>>>(qw, Wh, flag);
        f16_gemm256_kernel<<<NWG2, 512, 0, stream>>>(Ah, Wh, scale, bias, out);
    } else {
        w8_gemm_kernel<<<TM * TN, 256, 0, stream>>>(x, qw, scale, bias, out, flag);
    }
}